// Round 22
// baseline (757.004 us; speedup 1.0000x reference)
//
#include <hip/hip_runtime.h>

#define B_ 64
#define T_ 512
#define F_ 1024
#define U_ 64

// ---------------------------------------------------------------------------
// FUSED kernel: one block (8 waves, 512 thr) per batch.
//   waves 0-3 (consumer): VERBATIM R6 viterbi step (best measured, 235us,
//     absmax=0) -- serial 16-candidate chain, 2 __syncthreads/step, g0
//     combine. Only change: pot row comes from LDS (potl) instead of global.
//   waves 4-7 (producer): compute this batch's potentials = x@w + bias
//     (+boundaries) into potl[2][64][64] (double-buffered 64-row chunks),
//     one 16-k slice per consumer step, split across the two barrier
//     regions. Chunk c+1 completes at step c*64+63 (region 2); consumer
//     first reads it at step (c+1)*64 (region 1) -- barrier between.
//   GEMM arithmetic: ascending k, sequential fmaf per output -- bit-identical
//   to the validated standalone GEMM. Mechanism: viterbi is latency-bound
//   (VALUBusy 7.6%) -- the GEMM runs in its idle issue slots, removing the
//   serial ~110us GEMM dispatch entirely.
// LDS: potl 32KB + bp 32KB + misc ~ 67KB.
// ---------------------------------------------------------------------------
__global__ __launch_bounds__(512) void crf_fused_kernel(
    const float* __restrict__ x, const float* __restrict__ w,
    const float* __restrict__ bias, const float* __restrict__ chain,
    const float* __restrict__ lb, const float* __restrict__ rb,
    int* __restrict__ path)
{
    const int b = blockIdx.x;
    const int tid = threadIdx.x;
    const int lane = tid & 63;
    const int wave = tid >> 6;            // 0..7
    const bool cons = (wave < 4);
    const int g = wave & 3;               // consumer wave role
    const int u = lane;

    __shared__ __align__(16) float potl[2][64][64];   // 32 KB pot chunks
    __shared__ __align__(16) float alpha_s[64];
    __shared__ float pval[4][64];
    __shared__ int   pidx[4][64];
    __shared__ unsigned char bp[T_ - 1][64];          // 32704 B
    __shared__ unsigned char cmap[4][64];
    __shared__ int es[4];

    // ---------- prologue: chunk 0 (rows 0..63) by ALL 512 threads ----------
    {
        const int rt = tid >> 4;          // 32 groups x 2 rows
        const int u0 = (tid & 15) * 4;
        float a0[4] = {0.f, 0.f, 0.f, 0.f};
        float a1[4] = {0.f, 0.f, 0.f, 0.f};
        const float* xr = x + ((size_t)b * T_ + rt * 2) * F_;
        for (int k4 = 0; k4 < F_ / 4; ++k4) {
            const float4 x0 = *reinterpret_cast<const float4*>(xr + k4 * 4);
            const float4 x1 = *reinterpret_cast<const float4*>(xr + F_ + k4 * 4);
            const float4 w0 = *reinterpret_cast<const float4*>(w + (size_t)(k4 * 4 + 0) * U_ + u0);
            const float4 w1 = *reinterpret_cast<const float4*>(w + (size_t)(k4 * 4 + 1) * U_ + u0);
            const float4 w2 = *reinterpret_cast<const float4*>(w + (size_t)(k4 * 4 + 2) * U_ + u0);
            const float4 w3 = *reinterpret_cast<const float4*>(w + (size_t)(k4 * 4 + 3) * U_ + u0);
            a0[0] = fmaf(x0.x, w0.x, a0[0]); a0[1] = fmaf(x0.x, w0.y, a0[1]);
            a0[2] = fmaf(x0.x, w0.z, a0[2]); a0[3] = fmaf(x0.x, w0.w, a0[3]);
            a1[0] = fmaf(x1.x, w0.x, a1[0]); a1[1] = fmaf(x1.x, w0.y, a1[1]);
            a1[2] = fmaf(x1.x, w0.z, a1[2]); a1[3] = fmaf(x1.x, w0.w, a1[3]);
            a0[0] = fmaf(x0.y, w1.x, a0[0]); a0[1] = fmaf(x0.y, w1.y, a0[1]);
            a0[2] = fmaf(x0.y, w1.z, a0[2]); a0[3] = fmaf(x0.y, w1.w, a0[3]);
            a1[0] = fmaf(x1.y, w1.x, a1[0]); a1[1] = fmaf(x1.y, w1.y, a1[1]);
            a1[2] = fmaf(x1.y, w1.z, a1[2]); a1[3] = fmaf(x1.y, w1.w, a1[3]);
            a0[0] = fmaf(x0.z, w2.x, a0[0]); a0[1] = fmaf(x0.z, w2.y, a0[1]);
            a0[2] = fmaf(x0.z, w2.z, a0[2]); a0[3] = fmaf(x0.z, w2.w, a0[3]);
            a1[0] = fmaf(x1.z, w2.x, a1[0]); a1[1] = fmaf(x1.z, w2.y, a1[1]);
            a1[2] = fmaf(x1.z, w2.z, a1[2]); a1[3] = fmaf(x1.z, w2.w, a1[3]);
            a0[0] = fmaf(x0.w, w3.x, a0[0]); a0[1] = fmaf(x0.w, w3.y, a0[1]);
            a0[2] = fmaf(x0.w, w3.z, a0[2]); a0[3] = fmaf(x0.w, w3.w, a0[3]);
            a1[0] = fmaf(x1.w, w3.x, a1[0]); a1[1] = fmaf(x1.w, w3.y, a1[1]);
            a1[2] = fmaf(x1.w, w3.z, a1[2]); a1[3] = fmaf(x1.w, w3.w, a1[3]);
        }
        const float4 bs4 = *reinterpret_cast<const float4*>(bias + u0);
        const float4 lb4 = *reinterpret_cast<const float4*>(lb + u0);
        {
            float4 o;
            o.x = a0[0] + bs4.x; o.y = a0[1] + bs4.y;
            o.z = a0[2] + bs4.z; o.w = a0[3] + bs4.w;
            if (rt == 0) { o.x += lb4.x; o.y += lb4.y; o.z += lb4.z; o.w += lb4.w; }
            *reinterpret_cast<float4*>(&potl[0][rt * 2][u0]) = o;
        }
        {
            float4 o;
            o.x = a1[0] + bs4.x; o.y = a1[1] + bs4.y;
            o.z = a1[2] + bs4.z; o.w = a1[3] + bs4.w;
            *reinterpret_cast<float4*>(&potl[0][rt * 2 + 1][u0]) = o;
        }
    }

    // per-role persistent state
    float chain_r[16];
    const int prt = (tid & 255) >> 4;     // producer row-group (16 x 4 rows)
    const int pu0 = (tid & 15) * 4;       // producer col base
    float pacc[4][4];

// producer FMA for one k-quad (k = s*16 + KQ*4 + ff, ff ascending)
#define PROD_FMAQ(KQ)                                                         \
    {                                                                         \
        _Pragma("unroll")                                                     \
        for (int i = 0; i < 4; ++i) {                                         \
            pacc[i][0] = fmaf(xv[KQ][i].x, wv[KQ][0].x, pacc[i][0]);          \
            pacc[i][1] = fmaf(xv[KQ][i].x, wv[KQ][0].y, pacc[i][1]);          \
            pacc[i][2] = fmaf(xv[KQ][i].x, wv[KQ][0].z, pacc[i][2]);          \
            pacc[i][3] = fmaf(xv[KQ][i].x, wv[KQ][0].w, pacc[i][3]);          \
        }                                                                     \
        _Pragma("unroll")                                                     \
        for (int i = 0; i < 4; ++i) {                                         \
            pacc[i][0] = fmaf(xv[KQ][i].y, wv[KQ][1].x, pacc[i][0]);          \
            pacc[i][1] = fmaf(xv[KQ][i].y, wv[KQ][1].y, pacc[i][1]);          \
            pacc[i][2] = fmaf(xv[KQ][i].y, wv[KQ][1].z, pacc[i][2]);          \
            pacc[i][3] = fmaf(xv[KQ][i].y, wv[KQ][1].w, pacc[i][3]);          \
        }                                                                     \
        _Pragma("unroll")                                                     \
        for (int i = 0; i < 4; ++i) {                                         \
            pacc[i][0] = fmaf(xv[KQ][i].z, wv[KQ][2].x, pacc[i][0]);          \
            pacc[i][1] = fmaf(xv[KQ][i].z, wv[KQ][2].y, pacc[i][1]);          \
            pacc[i][2] = fmaf(xv[KQ][i].z, wv[KQ][2].z, pacc[i][2]);          \
            pacc[i][3] = fmaf(xv[KQ][i].z, wv[KQ][2].w, pacc[i][3]);          \
        }                                                                     \
        _Pragma("unroll")                                                     \
        for (int i = 0; i < 4; ++i) {                                         \
            pacc[i][0] = fmaf(xv[KQ][i].w, wv[KQ][3].x, pacc[i][0]);          \
            pacc[i][1] = fmaf(xv[KQ][i].w, wv[KQ][3].y, pacc[i][1]);          \
            pacc[i][2] = fmaf(xv[KQ][i].w, wv[KQ][3].z, pacc[i][2]);          \
            pacc[i][3] = fmaf(xv[KQ][i].w, wv[KQ][3].w, pacc[i][3]);          \
        }                                                                     \
    }

    if (cons) {
#pragma unroll
        for (int k = 0; k < 16; ++k)
            chain_r[k] = chain[(size_t)(g * 16 + k) * U_ + u];
    } else {
        // slice 0 of chunk 1 (reset + k 0..15)
#pragma unroll
        for (int i = 0; i < 4; ++i)
#pragma unroll
            for (int j = 0; j < 4; ++j) pacc[i][j] = 0.f;
        float4 xv[4][4], wv[4][4];
        const float* xr = x + ((size_t)b * T_ + 64 + prt * 4) * F_;
        const float* wr = w + pu0;
#pragma unroll
        for (int kq = 0; kq < 4; ++kq) {
#pragma unroll
            for (int i = 0; i < 4; ++i)
                xv[kq][i] = *reinterpret_cast<const float4*>(xr + (size_t)i * F_ + kq * 4);
#pragma unroll
            for (int j = 0; j < 4; ++j)
                wv[kq][j] = *reinterpret_cast<const float4*>(wr + (size_t)(kq * 4 + j) * U_);
        }
        PROD_FMAQ(0) PROD_FMAQ(1) PROD_FMAQ(2) PROD_FMAQ(3)
    }
    __syncthreads();

    if (cons && g == 0) alpha_s[u] = potl[0][0][u];   // t=0 (bias+left)
    __syncthreads();

    // ---------------- main loop ----------------
    for (int t = 1; t < T_; ++t) {
        const int c = (t >> 6) + 1;       // producer chunk this step
        const int s = t & 63;             // producer slice
        float4 xv[4][4], wv[4][4];        // producer regs (live over barrier1)

        if (cons) {
            // VERBATIM R6 consumer step (pot from LDS)
            const float pc = potl[(t >> 6) & 1][t & 63][u];
            const float4* a4 = reinterpret_cast<const float4*>(alpha_s);
            float best = -3.402823466e38f;
            int bidx = 0;
#pragma unroll
            for (int q = 0; q < 4; ++q) {
                const float4 av = a4[g * 4 + q];
                const float avv[4] = {av.x, av.y, av.z, av.w};
#pragma unroll
                for (int kk = 0; kk < 4; ++kk) {
                    const int k = q * 4 + kk;
                    const float s2 = (avv[kk] + chain_r[k]) + pc;
                    if (s2 > best) { best = s2; bidx = g * 16 + k; }
                }
            }
            pval[g][u] = best;
            pidx[g][u] = bidx;
        } else if (c < 8) {
            if (s == 0) {
#pragma unroll
                for (int i = 0; i < 4; ++i)
#pragma unroll
                    for (int j = 0; j < 4; ++j) pacc[i][j] = 0.f;
            }
            const float* xr = x + ((size_t)b * T_ + c * 64 + prt * 4) * F_ + s * 16;
            const float* wr = w + (size_t)(s * 16) * U_ + pu0;
#pragma unroll
            for (int kq = 0; kq < 4; ++kq) {
#pragma unroll
                for (int i = 0; i < 4; ++i)
                    xv[kq][i] = *reinterpret_cast<const float4*>(xr + (size_t)i * F_ + kq * 4);
#pragma unroll
                for (int j = 0; j < 4; ++j)
                    wv[kq][j] = *reinterpret_cast<const float4*>(wr + (size_t)(kq * 4 + j) * U_);
            }
            PROD_FMAQ(0) PROD_FMAQ(1)
        }
        __syncthreads();

        if (cons) {
            if (g == 0) {
                float bv = pval[0][u];
                int   bi = pidx[0][u];
#pragma unroll
                for (int j = 1; j < 4; ++j) {
                    const float v = pval[j][u];
                    if (v > bv) { bv = v; bi = pidx[j][u]; }  // lowest g on tie
                }
                bp[t - 1][u] = (unsigned char)bi;
                alpha_s[u] = bv;
            }
        } else if (c < 8) {
            PROD_FMAQ(2) PROD_FMAQ(3)
            if (s == 63) {
                const float4 bs4 = *reinterpret_cast<const float4*>(bias + pu0);
                const float4 rb4 = *reinterpret_cast<const float4*>(rb + pu0);
#pragma unroll
                for (int i = 0; i < 4; ++i) {
                    const int row = c * 64 + prt * 4 + i;
                    float4 o;
                    o.x = pacc[i][0] + bs4.x; o.y = pacc[i][1] + bs4.y;
                    o.z = pacc[i][2] + bs4.z; o.w = pacc[i][3] + bs4.w;
                    if (row == T_ - 1) { o.x += rb4.x; o.y += rb4.y; o.z += rb4.z; o.w += rb4.w; }
                    *reinterpret_cast<float4*>(&potl[c & 1][row & 63][pu0]) = o;
                }
            }
        }
        __syncthreads();
    }

    // ---------------- backtrace (validated 2-pass segmented) ----------------
    if (cons) {
        const int r0c = g * 128;
        const int r1c = (g == 3) ? (T_ - 1) : (g + 1) * 128;
        int tag = lane;
        for (int r = r1c - 1; r >= r0c; --r) tag = bp[r][tag];
        cmap[g][lane] = (unsigned char)tag;
    }
    __syncthreads();

    if (tid == 0) {
        float bvv = alpha_s[0];
        int bii = 0;
        for (int v = 1; v < 64; ++v) {
            const float a = alpha_s[v];
            if (a > bvv) { bvv = a; bii = v; }   // strict >: first occurrence
        }
        path[(size_t)b * T_ + (T_ - 1)] = bii;
        const int e3 = bii;                 // tag_511
        const int e2 = cmap[3][e3];         // tag_384
        const int e1 = cmap[2][e2];         // tag_256
        const int e0 = cmap[1][e1];         // tag_128
        es[0] = e0; es[1] = e1; es[2] = e2; es[3] = e3;
    }
    __syncthreads();

    if (cons && lane == 0) {
        const int r0c = g * 128;
        const int r1c = (g == 3) ? (T_ - 1) : (g + 1) * 128;
        int tag = es[g];
        int* pb = path + (size_t)b * T_;
        for (int r = r1c - 1; r >= r0c; --r) {
            tag = bp[r][tag];
            pb[r] = tag;
        }
    }
#undef PROD_FMAQ
}

extern "C" void kernel_launch(void* const* d_in, const int* in_sizes, int n_in,
                              void* d_out, int out_size, void* d_ws, size_t ws_size,
                              hipStream_t stream) {
    const float* x  = (const float*)d_in[0];
    const float* w  = (const float*)d_in[1];
    const float* bs = (const float*)d_in[2];
    const float* ck = (const float*)d_in[3];
    const float* lb = (const float*)d_in[4];
    const float* rb = (const float*)d_in[5];
    int* path = (int*)d_out;            // [B][T] int32

    crf_fused_kernel<<<dim3(B_), dim3(512), 0, stream>>>(x, w, bs, ck, lb, rb, path);
}